// Round 6
// baseline (330.691 us; speedup 1.0000x reference)
//
#include <hip/hip_runtime.h>

// Problem constants
#define Bsz 16384
#define Isz 512
#define Hsz 512
#define Ksz 1024   // I + H
#define N4H 2048   // 4*H

// GEMM tile (256x256, 8-phase schedule)
#define BM 256
#define BN 256
#define BK 64

typedef __bf16 bf16x8 __attribute__((ext_vector_type(8)));
typedef __bf16 bf16x4 __attribute__((ext_vector_type(4)));
typedef float  f32x4  __attribute__((ext_vector_type(4)));

__device__ __forceinline__ void async_copy16(const void* g, void* l) {
    __builtin_amdgcn_global_load_lds(
        (__attribute__((address_space(1))) void*)g,
        (__attribute__((address_space(3))) void*)l,
        16, 0, 0);
}

// ---------------------------------------------------------------------------
// Combined pack kernel — ROUND-6: grid-stride over 2048 blocks.
// Round 0-5 launched 18,432 tiny blocks (4 KB work each); workgroup dispatch
// rate alone is O(tens of us) at that count (Guideline 11). Index math is
// byte-identical: virtual block vb = blockIdx.x + 2048*it, it = 0..8.
//   vb in [0,16384): activations  Aq[b][k] = bf16([input|h_prev][b][k])
//   vb in [16384,18432): weights, gate-interleaved row permutation + bias.
//     Permuted row p: nb=p/128, n=p%128; wn=n>>6, gate=(n>>4)&3, c=n&15
//     -> original row = gate*512 + nb*32 + wn*16 + c.
// ---------------------------------------------------------------------------
__global__ __launch_bounds__(256) void pack_all(
        const float* __restrict__ x, const float* __restrict__ h,
        const float* __restrict__ Wxh, const float* __restrict__ Whh,
        const float* __restrict__ bxh, const float* __restrict__ bhh,
        __bf16* __restrict__ Aq, __bf16* __restrict__ Bq,
        float* __restrict__ bias) {
#pragma unroll 1
    for (int vb = blockIdx.x; vb < 18432; vb += 2048) {
        if (vb < 16384) {
            int idx = vb * 256 + threadIdx.x;
            int e   = idx << 2;                 // 4 elements per thread
            int row = e >> 10, col = e & 1023;  // col multiple of 4
            const float4 v = (col < Isz)
                ? *(const float4*)(x + (size_t)row * Isz + col)
                : *(const float4*)(h + (size_t)row * Hsz + (col - Isz));
            bf16x4 o = { (__bf16)v.x, (__bf16)v.y, (__bf16)v.z, (__bf16)v.w };
            *(bf16x4*)(Aq + (size_t)e) = o;
        } else {
            int idx = (vb - 16384) * 256 + threadIdx.x;
            int p   = idx >> 8;            // permuted row
            int k   = (idx & 255) << 2;
            int nb  = p >> 7, n = p & 127;
            int wn  = n >> 6, t = (n >> 4) & 3, c = n & 15;
            int orow = t * Hsz + nb * 32 + wn * 16 + c;
            const float4 v = (k < Isz)
                ? *(const float4*)(Wxh + (size_t)orow * Isz + k)
                : *(const float4*)(Whh + (size_t)orow * Hsz + (k - Isz));
            bf16x4 o = { (__bf16)v.x, (__bf16)v.y, (__bf16)v.z, (__bf16)v.w };
            *(bf16x4*)(Bq + (size_t)p * Ksz + k) = o;
            if ((idx & 255) == 0) bias[p] = bxh[orow] + bhh[orow];
        }
    }
}

// ---------------------------------------------------------------------------
// Fused GEMM + sLSTM epilogue — UNCHANGED from round 5 (scored-best total).
// 256x256 tile, 8-wave, 8-phase schedule; inline-asm ds_read_b128, counted
// vmcnt(4) at phases 4/8, lgkmcnt(0)+sched_barrier(0) before MFMA, LDS XOR
// swizzle (0 bank conflicts), plain 2-D grid (compulsory-only FETCH 98 MB),
// fast-math epilogue (v_exp/v_rcp).
// ---------------------------------------------------------------------------
#define CFENCE asm volatile("" ::: "memory")
#define BARRIER { CFENCE; __builtin_amdgcn_s_barrier(); CFENCE; }
#define WAITLGKM { asm volatile("s_waitcnt lgkmcnt(0)" ::: "memory"); \
                   __builtin_amdgcn_sched_barrier(0); }
#define WAITVM4  asm volatile("s_waitcnt vmcnt(4)" ::: "memory")

// LDS byte address (32-bit) of a pointer into a __shared__ array.
#define LDSA(p) ((unsigned)(size_t)(const __bf16 __attribute__((address_space(3)))*)(p))

#define DSR(dst, addr, IMM) \
    asm volatile("ds_read_b128 %0, %1 offset:" IMM : "=v"(dst) : "v"(addr))

// A fragments: af[f][kk] <- rows (fbase+f)*16 above base, k-group kk.
#define LDS_A_(ap, I0, I1, I2, I3) { \
    const unsigned a0_ = LDSA((ap) + ko0), a1_ = LDSA((ap) + ko1); \
    DSR(af[0][0], a0_, I0); DSR(af[0][1], a1_, I0); \
    DSR(af[1][0], a0_, I1); DSR(af[1][1], a1_, I1); \
    DSR(af[2][0], a0_, I2); DSR(af[2][1], a1_, I2); \
    DSR(af[3][0], a0_, I3); DSR(af[3][1], a1_, I3); }
#define LDS_A0(ap) LDS_A_(ap, "0", "2048", "4096", "6144")
#define LDS_A4(ap) LDS_A_(ap, "8192", "10240", "12288", "14336")

#define LDS_B0(bp) { \
    const unsigned b0_ = LDSA((bp) + ko0), b1_ = LDSA((bp) + ko1); \
    DSR(bf[0][0], b0_, "0");    DSR(bf[0][1], b1_, "0"); \
    DSR(bf[1][0], b0_, "2048"); DSR(bf[1][1], b1_, "2048"); }
#define LDS_B2(bp) { \
    const unsigned b0_ = LDSA((bp) + ko0), b1_ = LDSA((bp) + ko1); \
    DSR(bf[2][0], b0_, "4096"); DSR(bf[2][1], b1_, "4096"); \
    DSR(bf[3][0], b0_, "6144"); DSR(bf[3][1], b1_, "6144"); }

#define MMA(fbase, nbase)                                                     \
    __builtin_amdgcn_s_setprio(1);                                            \
    _Pragma("unroll") for (int f = 0; f < 4; ++f)                             \
    _Pragma("unroll") for (int n = 0; n < 2; ++n)                             \
    _Pragma("unroll") for (int kk = 0; kk < 2; ++kk)                          \
        acc[(fbase) + f][(nbase) + n] = __builtin_amdgcn_mfma_f32_16x16x32_bf16( \
            af[f][kk], bf[(nbase) + n][kk], acc[(fbase) + f][(nbase) + n], 0, 0, 0); \
    __builtin_amdgcn_s_setprio(0);

// One half-tile = 128 rows x 64 cols bf16 = 16 KiB = 2 gload_lds / thread.
#define STAGE(dst, src, half, step)                                           \
    { async_copy16((src) + (size_t)((half) * 128 + rrow) * Ksz + (step) * 64 + scol, \
                   (char*)(dst) + (half) * 16384 + tid * 16);                 \
      async_copy16((src) + (size_t)((half) * 128 + 64 + rrow) * Ksz + (step) * 64 + scol, \
                   (char*)(dst) + (half) * 16384 + 8192 + tid * 16); }

__global__ __launch_bounds__(512, 2) void slstm_gemm(
    const __bf16* __restrict__ Aq, const __bf16* __restrict__ Bq,
    const float* __restrict__ bias,
    const float* __restrict__ c_prev, const float* __restrict__ m_prev,
    const float* __restrict__ n_prev, float* __restrict__ out) {

    __shared__ __bf16 As0[BM * BK];   // 32 KiB each, 128 KiB total
    __shared__ __bf16 As1[BM * BK];
    __shared__ __bf16 Bs0[BN * BK];
    __shared__ __bf16 Bs1[BN * BK];

    const int tid  = threadIdx.x;
    const int w    = tid >> 6;
    const int lane = tid & 63;
    const int wm   = w & 1;          // wave M row (0..1) -> 128 rows each
    const int wc   = w >> 1;         // wave N col (0..3) -> 64 cols each

    const int bm  = blockIdx.x;      // batch tile (0..63)
    const int nbb = blockIdx.y;      // 256-wide gate-col tile (0..7)

    const int lr = lane & 15;
    const int g0 = lane >> 4;        // 0..3
    const int px = lr & 7;

    const __bf16* Ag = Aq + (size_t)bm  * BM * Ksz;
    const __bf16* Bg = Bq + (size_t)nbb * BN * Ksz;

    // staging geometry
    const int rrow = tid >> 3;                    // 0..63
    const int scol = ((tid & 7) ^ (rrow & 7)) * 8;

    // fragment-read bases (swizzled k-group offsets; row&7 == lr&7 always)
    const __bf16* A0p = &As0[(wm * 128 + lr) * 64];
    const __bf16* A1p = &As1[(wm * 128 + lr) * 64];
    const __bf16* B0p = &Bs0[(wc * 64 + lr) * 64];
    const __bf16* B1p = &Bs1[(wc * 64 + lr) * 64];
    const int ko0 = ((0 * 4 + g0) ^ px) * 8;
    const int ko1 = ((1 * 4 + g0) ^ px) * 8;

    f32x4 acc[8][4];
    const f32x4 zero = {0.f, 0.f, 0.f, 0.f};
#pragma unroll
    for (int mi = 0; mi < 8; ++mi)
#pragma unroll
        for (int ni = 0; ni < 4; ++ni) acc[mi][ni] = zero;

    // ---------------- prologue: stage b0 step0 fully + B(b1) step1 ----------
    STAGE(Bs0, Bg, 0, 0);
    STAGE(Bs0, Bg, 1, 0);
    STAGE(As0, Ag, 0, 0);
    STAGE(As0, Ag, 1, 0);
    STAGE(Bs1, Bg, 0, 1);
    STAGE(Bs1, Bg, 1, 1);
    WAITVM4;            // b0 step0 complete; B(b1) step1 (4 loads) in flight
    BARRIER;

    bf16x8 af[4][2];
    bf16x8 bf[4][2];

#pragma unroll 1
    for (int i = 0; i < 8; ++i) {
        const int ic  = (i < 7) ? i : 6;
        const int sA1 = 2 * i + 1;       // A(b1) for this iteration's odd step
        const int sB0 = 2 * ic + 2;      // next even step into b0 (clamped)
        const int sB1 = 2 * ic + 3;      // next odd step into b1 (clamped)

        // ---- p0 (b0, quad 0,0): read A[0..3], B[0..1] ----
        LDS_A0(A0p);
        LDS_B0(B0p);
        STAGE(As1, Ag, 0, sA1);
        BARRIER; WAITLGKM;
        MMA(0, 0);
        BARRIER;

        // ---- p1 (b0, quad 0,1): read B[2..3] ----
        LDS_B2(B0p);
        STAGE(As1, Ag, 1, sA1);
        BARRIER; WAITLGKM;
        MMA(0, 2);
        BARRIER;

        // ---- p2 (b0, quad 1,1): read A[4..7] ----
        LDS_A4(A0p);
        STAGE(Bs0, Bg, 0, sB0);
        BARRIER; WAITLGKM;
        MMA(4, 2);
        BARRIER;

        // ---- p3 (b0, quad 1,0): no reads (bf[0..1] live from p0) ----
        STAGE(Bs0, Bg, 1, sB0);
        BARRIER;
        MMA(4, 0);
        WAITVM4;         // A/B(b1) step 2i+1 complete; p2+p3 stages in flight
        BARRIER;

        // ---- p4 (b1, quad 0,0) ----
        LDS_A0(A1p);
        LDS_B0(B1p);
        STAGE(As0, Ag, 0, sB0);
        BARRIER; WAITLGKM;
        MMA(0, 0);
        BARRIER;

        // ---- p5 (b1, quad 0,1) ----
        LDS_B2(B1p);
        STAGE(As0, Ag, 1, sB0);
        BARRIER; WAITLGKM;
        MMA(0, 2);
        BARRIER;

        // ---- p6 (b1, quad 1,1) ----
        LDS_A4(A1p);
        STAGE(Bs1, Bg, 0, sB1);
        BARRIER; WAITLGKM;
        MMA(4, 2);
        BARRIER;

        // ---- p7 (b1, quad 1,0) ----
        STAGE(Bs1, Bg, 1, sB1);
        BARRIER;
        MMA(4, 0);
        WAITVM4;         // b0 step 2i+2 complete; p6+p7 stages in flight
        BARRIER;
    }

    // ---------------- fused sLSTM epilogue (fast-math) ----------------------
    // Wave wc's 4 N-fragments are the 4 gates of the same 16 h values.
    const int hidx = (nbb * 2 + (wc >> 1)) * 32 + (wc & 1) * 16 + lr;

    float bsv[4];
#pragma unroll
    for (int n = 0; n < 4; ++n)
        bsv[n] = bias[nbb * 256 + wc * 64 + n * 16 + lr];

    const size_t BH = (size_t)Bsz * Hsz;
    const float L2E  = 1.44269504089f;   // log2(e)
    const float L2E2 = 2.88539008178f;   // 2*log2(e)

#pragma unroll
    for (int mi = 0; mi < 8; ++mi) {
        const int mbase = bm * 256 + wm * 128 + mi * 16 + g0 * 4;
#pragma unroll
        for (int r = 0; r < 4; ++r) {
            const int m = mbase + r;
            const size_t off = (size_t)m * Hsz + hidx;
            const float ig = acc[mi][0][r] + bsv[0];
            const float fg = acc[mi][1][r] + bsv[1];
            const float zg = acc[mi][2][r] + bsv[2];
            const float og = acc[mi][3][r] + bsv[3];
            const float cp = c_prev[off];
            const float mp = m_prev[off];
            const float np = n_prev[off];
            // tanh(zg) = 1 - 2/(exp2(2*zg*log2e)+1)  (saturates to +-1 cleanly)
            const float zt = 1.f - 2.f * __builtin_amdgcn_rcpf(
                                 __builtin_amdgcn_exp2f(zg * L2E2) + 1.f);
            // sigmoid(og) = 1/(1+exp2(-og*log2e))
            const float ot = __builtin_amdgcn_rcpf(
                                 __builtin_amdgcn_exp2f(-og * L2E) + 1.f);
            const float fm = fg + mp;
            const float mt = fmaxf(fm, ig);
            const float it = __builtin_amdgcn_exp2f((ig - mt) * L2E);
            const float ft = __builtin_amdgcn_exp2f((fm - mt) * L2E);
            const float ct = ft * cp + it * zt;
            const float nt = ft * np + it;
            const float ht = ot * ct * __builtin_amdgcn_rcpf(nt);
            out[off]          = ht;
            out[BH + off]     = ct;
            out[2 * BH + off] = mt;
            out[3 * BH + off] = nt;
        }
    }
}

// ---------------------------------------------------------------------------
extern "C" void kernel_launch(void* const* d_in, const int* in_sizes, int n_in,
                              void* d_out, int out_size, void* d_ws, size_t ws_size,
                              hipStream_t stream) {
    const float* input  = (const float*)d_in[0];
    const float* h_prev = (const float*)d_in[1];
    const float* c_prev = (const float*)d_in[2];
    const float* m_prev = (const float*)d_in[3];
    const float* n_prev = (const float*)d_in[4];
    const float* Wxh    = (const float*)d_in[5];
    const float* bxh    = (const float*)d_in[6];
    const float* Whh    = (const float*)d_in[7];
    const float* bhh    = (const float*)d_in[8];
    float* out = (float*)d_out;

    // Workspace layout: Aq (32 MiB bf16) | Bq (4 MiB bf16) | bias (8 KiB f32)
    __bf16* Aq   = (__bf16*)d_ws;
    __bf16* Bq   = (__bf16*)((char*)d_ws + (size_t)Bsz * Ksz * 2);
    float*  bias = (float*)((char*)d_ws + (size_t)Bsz * Ksz * 2 + (size_t)N4H * Ksz * 2);

    // Grid-stride pack: 2048 blocks cover the 18432 virtual blocks.
    pack_all<<<2048, 256, 0, stream>>>(input, h_prev, Wxh, Whh, bxh, bhh,
                                       Aq, Bq, bias);

    dim3 grid(Bsz / BM, N4H / BN);
    slstm_gemm<<<grid, 512, 0, stream>>>(Aq, Bq, bias, c_prev, m_prev, n_prev, out);
}